// Round 6
// baseline (166.493 us; speedup 1.0000x reference)
//
#include <hip/hip_runtime.h>
#include <hip/hip_bf16.h>
#include <stdint.h>

#define KDIM    256
#define NWORDS  1564         // sign words per column: 782 bm-tiles * 2
#define NW      1563         // crossing words (ceil(99999/64))
#define GEMM_GRID 1564       // 782 bm * 2 bn

typedef float  f32x4  __attribute__((ext_vector_type(4)));
typedef __bf16 bf16x8 __attribute__((ext_vector_type(8)));

__device__ __forceinline__ void gl_lds16(const void* g, void* l) {
    __builtin_amdgcn_global_load_lds(
        (const __attribute__((address_space(1))) unsigned int*)g,
        (__attribute__((address_space(3))) unsigned int*)l, 16, 0, 0);
}

// ---------- K0: build W bf16 [512 rows j][512 cols d] ----------
__global__ void build_w(const float* __restrict__ theta,
                        const float* __restrict__ noise,
                        __bf16* __restrict__ W) {
    int idx = blockIdx.x * 256 + threadIdx.x;   // 0..262143
    int j = idx >> 9;
    int d = idx & 511;
    float v;
    if (j < KDIM) v = theta[j * 512 + d];
    else          v = theta[(j - KDIM) * 512 + d] + 0.01f * noise[(j - KDIM) * 512 + d];
    W[idx] = (__bf16)v;
}

// ---------- K1: 8-phase-style MFMA GEMM -> packed sign bits ----------
// BM=128 x BN=256, BK=64, 512 threads (8 waves 2Mx4N, wave-tile 64x64).
// 8 K-tiles; per tile 4 sub-phases of 8 MFMA each, barriers between phases.
// A: global f32 (4 loads/thr, issued phase 0) -> phase-3 vmcnt(4) -> cvt ->
//    XOR-swizzled ds_write_b128 into next parity buffer (write-late, T14).
// B: 4x global_load_lds DMA (source-granule swizzled), issued phase 0.
// Iter-start wait vmcnt(8): all 8 next-tile VM ops stay in flight across
// every barrier (T4 counted vmcnt). LDS: A 2x16KB + B 2x32KB = 96KB.
__global__ void __launch_bounds__(512, 2)
gemm_signs(const float* __restrict__ basis,
           const __bf16* __restrict__ W,
           uint64_t* __restrict__ sbits) {
    __shared__ char smem[98304];   // A: [2][128r][128B] @0; B: [2][256c][128B] @32768

    const int tid    = threadIdx.x;
    const int lane   = tid & 63;
    const int wave   = tid >> 6;
    const int wr     = wave >> 2;      // 0..1
    const int wc     = wave & 3;       // 0..3
    const int lane16 = lane & 15;
    const int lgrp   = lane >> 4;

    // bijective XCD swizzle: nwg=1564=8*195+4 (m204): adjacent wgid -> same XCD
    const int orig = blockIdx.x;
    const int xcd  = orig & 7;
    const int wgid = (xcd < 4 ? xcd * 196 : 784 + (xcd - 4) * 195) + (orig >> 3);
    const int bn   = wgid & 1;     // 0..1
    const int bm   = wgid >> 1;    // 0..781

    // ---- A staging geometry: thread -> (row ar, octets ah0=2*(tid&3), +1) ----
    const int ar  = tid >> 2;          // 0..127
    const int ah0 = (tid & 3) * 2;     // 0,2,4,6
    int arg = bm * 128 + ar; if (arg > 99999) arg = 99999;   // tail clamp
    const float* ag0 = basis + (size_t)arg * 512 + ah0 * 8;
    const float* ag1 = ag0 + 8;
    const int aw0 = ar * 128 + (((ah0    ) ^ (ar & 7)) << 4);  // swizzled LDS ofs
    const int aw1 = ar * 128 + (((ah0 + 1) ^ (ar & 7)) << 4);

    // ---- B DMA staging: 4 rounds of 8 cols x 8 granules per wave ----
    auto stage_B = [&](int t) {
        char* bbase = smem + 32768 + ((t & 1) << 15);
        #pragma unroll
        for (int i = 0; i < 4; ++i) {
            int c = wave * 32 + i * 8 + (lane >> 3);   // local col 0..255
            int g = lane & 7;                          // 16B granule in 128B row
            const __bf16* src = W + (size_t)(bn * 256 + c) * 512 + t * 64
                                  + ((g ^ (c & 7)) << 3);
            gl_lds16(src, bbase + (wave * 32 + i * 8) * 128);  // uniform+lane*16
        }
    };

    f32x4  acc[4][4] = {};
    float4 ra[2][2];

    auto cvt_write_A = [&](int q) {    // regs -> bf16 -> swizzled LDS buffer q
        char* abase = smem + (q << 14);
        #pragma unroll
        for (int u = 0; u < 2; ++u) {
            bf16x8 a8;
            a8[0] = (__bf16)ra[u][0].x; a8[1] = (__bf16)ra[u][0].y;
            a8[2] = (__bf16)ra[u][0].z; a8[3] = (__bf16)ra[u][0].w;
            a8[4] = (__bf16)ra[u][1].x; a8[5] = (__bf16)ra[u][1].y;
            a8[6] = (__bf16)ra[u][1].z; a8[7] = (__bf16)ra[u][1].w;
            *(bf16x8*)(abase + (u ? aw1 : aw0)) = a8;
        }
    };

    // ---- prologue: A(0) loads + B(0) DMA; drain A only; write As[0] ----
    ra[0][0] = *(const float4*)(ag0);  ra[0][1] = *(const float4*)(ag0 + 4);
    ra[1][0] = *(const float4*)(ag1);  ra[1][1] = *(const float4*)(ag1 + 4);
    stage_B(0);
    asm volatile("s_waitcnt vmcnt(4)" ::: "memory");   // A(0) regs ready; B(0) in flight
    cvt_write_A(0);

    #pragma unroll
    for (int t = 0; t < 8; ++t) {
        const int p = t & 1, q = (t + 1) & 1;
        const char* ab = smem + (p << 14);
        const char* bb = smem + 32768 + (p << 15);

        // ---- phase 0: issue next-tile staging; tile-ready wait; 8 MFMA ----
        if (t < 7) {
            ra[0][0] = *(const float4*)(ag0 + (t + 1) * 64);
            ra[0][1] = *(const float4*)(ag0 + (t + 1) * 64 + 4);
            ra[1][0] = *(const float4*)(ag1 + (t + 1) * 64);
            ra[1][1] = *(const float4*)(ag1 + (t + 1) * 64 + 4);
            stage_B(t + 1);
            asm volatile("s_waitcnt vmcnt(8) lgkmcnt(0)\ns_barrier" ::: "memory");
        } else {
            asm volatile("s_waitcnt vmcnt(0) lgkmcnt(0)\ns_barrier" ::: "memory");
        }

        bf16x8 bf[4], af[2];
        #pragma unroll
        for (int n = 0; n < 4; ++n) {                 // bf for ks=0
            int cc = wc * 64 + n * 16 + lane16;
            bf[n] = *(const bf16x8*)(bb + cc * 128 + (((0 + lgrp) ^ (cc & 7)) << 4));
        }
        #pragma unroll
        for (int mi = 0; mi < 2; ++mi) {              // af ks=0, mh=0
            int rr = wr * 64 + mi * 16 + lane16;
            af[mi] = *(const bf16x8*)(ab + rr * 128 + (((0 + lgrp) ^ (rr & 7)) << 4));
        }
        asm volatile("s_waitcnt lgkmcnt(0)" ::: "memory");
        __builtin_amdgcn_sched_barrier(0);
        __builtin_amdgcn_s_setprio(1);
        #pragma unroll
        for (int mi = 0; mi < 2; ++mi)
            #pragma unroll
            for (int n = 0; n < 4; ++n)
                acc[mi][n] = __builtin_amdgcn_mfma_f32_16x16x32_bf16(af[mi], bf[n], acc[mi][n], 0, 0, 0);
        __builtin_amdgcn_s_setprio(0);
        asm volatile("s_barrier" ::: "memory");

        // ---- phase 1: af ks=0, mh=1 ----
        #pragma unroll
        for (int mi = 0; mi < 2; ++mi) {
            int rr = wr * 64 + (2 + mi) * 16 + lane16;
            af[mi] = *(const bf16x8*)(ab + rr * 128 + (((0 + lgrp) ^ (rr & 7)) << 4));
        }
        asm volatile("s_waitcnt lgkmcnt(0)" ::: "memory");
        __builtin_amdgcn_sched_barrier(0);
        __builtin_amdgcn_s_setprio(1);
        #pragma unroll
        for (int mi = 0; mi < 2; ++mi)
            #pragma unroll
            for (int n = 0; n < 4; ++n)
                acc[2 + mi][n] = __builtin_amdgcn_mfma_f32_16x16x32_bf16(af[mi], bf[n], acc[2 + mi][n], 0, 0, 0);
        __builtin_amdgcn_s_setprio(0);
        asm volatile("s_barrier" ::: "memory");

        // ---- phase 2: bf ks=1; af ks=1, mh=0 ----
        #pragma unroll
        for (int n = 0; n < 4; ++n) {
            int cc = wc * 64 + n * 16 + lane16;
            bf[n] = *(const bf16x8*)(bb + cc * 128 + (((4 + lgrp) ^ (cc & 7)) << 4));
        }
        #pragma unroll
        for (int mi = 0; mi < 2; ++mi) {
            int rr = wr * 64 + mi * 16 + lane16;
            af[mi] = *(const bf16x8*)(ab + rr * 128 + (((4 + lgrp) ^ (rr & 7)) << 4));
        }
        asm volatile("s_waitcnt lgkmcnt(0)" ::: "memory");
        __builtin_amdgcn_sched_barrier(0);
        __builtin_amdgcn_s_setprio(1);
        #pragma unroll
        for (int mi = 0; mi < 2; ++mi)
            #pragma unroll
            for (int n = 0; n < 4; ++n)
                acc[mi][n] = __builtin_amdgcn_mfma_f32_16x16x32_bf16(af[mi], bf[n], acc[mi][n], 0, 0, 0);
        __builtin_amdgcn_s_setprio(0);
        asm volatile("s_barrier" ::: "memory");

        // ---- phase 3: af ks=1, mh=1; drain A(t+1) regs; cvt+write-late ----
        #pragma unroll
        for (int mi = 0; mi < 2; ++mi) {
            int rr = wr * 64 + (2 + mi) * 16 + lane16;
            af[mi] = *(const bf16x8*)(ab + rr * 128 + (((4 + lgrp) ^ (rr & 7)) << 4));
        }
        if (t < 7) {
            asm volatile("s_waitcnt vmcnt(4)" ::: "memory");  // 4 oldest = A(t+1) regs
            cvt_write_A(q);
        }
        asm volatile("s_waitcnt lgkmcnt(0)" ::: "memory");
        __builtin_amdgcn_sched_barrier(0);
        __builtin_amdgcn_s_setprio(1);
        #pragma unroll
        for (int mi = 0; mi < 2; ++mi)
            #pragma unroll
            for (int n = 0; n < 4; ++n)
                acc[2 + mi][n] = __builtin_amdgcn_mfma_f32_16x16x32_bf16(af[mi], bf[n], acc[2 + mi][n], 0, 0, 0);
        __builtin_amdgcn_s_setprio(0);
        asm volatile("s_barrier" ::: "memory");
    }

    // ---- epilogue: sign bytes -> LDS transpose -> multiply-pack -> u64 ----
    // C/D layout: col = lane&15, row = (lane>>4)*4 + reg
    unsigned char* sb = (unsigned char*)smem;     // [256 cols][136B] = 34.8KB
    #pragma unroll
    for (int m = 0; m < 4; ++m) {
        #pragma unroll
        for (int n = 0; n < 4; ++n) {
            int cc = wc * 64 + n * 16 + lane16;          // local col 0..255
            int rb = wr * 64 + m * 16 + lgrp * 4;        // local row base 0..124
            uint32_t pk = 0;
            #pragma unroll
            for (int r = 0; r < 4; ++r)
                pk |= (acc[m][n][r] < 0.0f ? 1u : 0u) << (8 * r);
            *(uint32_t*)&sb[cc * 136 + rb] = pk;
        }
    }
    asm volatile("s_waitcnt lgkmcnt(0)\ns_barrier" ::: "memory");

    {   // thread -> (col 0..255, word-half 0..1); 64 sign bytes -> u64
        const int col = tid & 255;
        const int wh  = tid >> 8;
        const unsigned char* src = &sb[col * 136 + wh * 64];
        uint64_t wbits = 0;
        #pragma unroll
        for (int k = 0; k < 16; ++k) {
            uint32_t qv = *(const uint32_t*)&src[4 * k];
            uint32_t p4 = ((qv & 0x01010101u) * 0x10204080u) >> 28;
            wbits |= (uint64_t)p4 << (4 * k);
        }
        sbits[(size_t)(bm * 2 + wh) * 512 + bn * 256 + col] = wbits;  // coalesced
    }
}

// ---------- K2: crossing masks from sign bits ----------
__global__ void crossing_masks(const uint64_t* __restrict__ sbits,
                               uint64_t* __restrict__ maskT) {
    const int w = blockIdx.x;       // 0..1562
    const int j = threadIdx.x;      // 0..255
    uint64_t s0r = sbits[(size_t)w * 512 + j];
    uint64_t s0p = sbits[(size_t)w * 512 + 256 + j];
    uint64_t s1r = sbits[(size_t)(w + 1) * 512 + j];
    uint64_t s1p = sbits[(size_t)(w + 1) * 512 + 256 + j];
    uint64_t cr = s0r ^ ((s0r >> 1) | (s1r << 63));
    uint64_t cp = s0p ^ ((s0p >> 1) | (s1p << 63));
    uint64_t m = cr & cp;
    if (w == NW - 1) m &= 0x7FFFFFFFull;    // 31 valid crossings in last word
    maskT[(size_t)w * 256 + j] = m;
}

// ---------- K3: pairwise AND-popcount ----------
__global__ void zero_out(float* __restrict__ out) {
    int i = blockIdx.x * 256 + threadIdx.x;
    if (i < 32640) out[i] = 0.0f;
}

__global__ void pair_popcount(const uint64_t* __restrict__ maskT,
                              float* __restrict__ out) {
    const int i = blockIdx.x;   // 0..255
    const int c = blockIdx.y;   // 0..7 word chunk
    const int j = threadIdx.x;  // 0..255
    if (j <= i) return;
    int w0 = c * 196;
    int w1 = w0 + 196; if (w1 > NW) w1 = NW;
    uint32_t sum = 0;
    #pragma unroll 4
    for (int w = w0; w < w1; ++w) {
        uint64_t mi = maskT[(size_t)w * 256 + i];   // block-uniform -> scalar
        uint64_t mj = maskT[(size_t)w * 256 + j];   // coalesced
        sum += (uint32_t)__popcll(mi & mj);
    }
    const size_t idx = (size_t)i * (2 * KDIM - i - 1) / 2 + (size_t)(j - i - 1);
    atomicAdd(&out[idx], (float)sum);   // exact-integer f32 adds -> deterministic
}

extern "C" void kernel_launch(void* const* d_in, const int* in_sizes, int n_in,
                              void* d_out, int out_size, void* d_ws, size_t ws_size,
                              hipStream_t stream) {
    const float* theta = (const float*)d_in[0];   // [256,512]
    const float* basis = (const float*)d_in[1];   // [100000,512]
    const float* noise = (const float*)d_in[2];   // [256,512]
    float* out = (float*)d_out;                   // [32640]

    char* ws = (char*)d_ws;
    __bf16*   W     = (__bf16*)ws;                              // 512 KB
    uint64_t* sbits = (uint64_t*)(ws + 524288);                 // 1564*512*8 = 6.41 MB
    uint64_t* maskT = (uint64_t*)(ws + 524288 + (size_t)NWORDS * 512 * 8); // 3.2 MB

    hipLaunchKernelGGL(build_w,        dim3(1024),     dim3(256), 0, stream, theta, noise, W);
    hipLaunchKernelGGL(gemm_signs,     dim3(GEMM_GRID),dim3(512), 0, stream, basis, W, sbits);
    hipLaunchKernelGGL(crossing_masks, dim3(NW),       dim3(256), 0, stream, sbits, maskT);
    hipLaunchKernelGGL(zero_out,       dim3(128),      dim3(256), 0, stream, out);
    hipLaunchKernelGGL(pair_popcount,  dim3(KDIM, 8),  dim3(256), 0, stream, maskT, out);
}

// Round 7
// 155.466 us; speedup vs baseline: 1.0709x; 1.0709x over previous
//
#include <hip/hip_runtime.h>
#include <hip/hip_bf16.h>
#include <stdint.h>

#define KDIM    256
#define NWORDS  1564         // sign words per column
#define NW      1563         // crossing words (ceil(99999/64))

typedef float  f32x4  __attribute__((ext_vector_type(4)));
typedef __bf16 bf16x8 __attribute__((ext_vector_type(8)));
typedef __bf16 bf16x4 __attribute__((ext_vector_type(4)));

__device__ __forceinline__ void gl_lds16(const void* g, void* l) {
    __builtin_amdgcn_global_load_lds(
        (const __attribute__((address_space(1))) unsigned int*)g,
        (__attribute__((address_space(3))) unsigned int*)l, 16, 0, 0);
}

// ---------- K0: build W bf16 [512 rows j][512 cols d] ----------
__global__ void build_w(const float* __restrict__ theta,
                        const float* __restrict__ noise,
                        __bf16* __restrict__ W) {
    int idx = blockIdx.x * 256 + threadIdx.x;   // 0..262143
    int j = idx >> 9;
    int d = idx & 511;
    float v;
    if (j < KDIM) v = theta[j * 512 + d];
    else          v = theta[(j - KDIM) * 512 + d] + 0.01f * noise[(j - KDIM) * 512 + d];
    W[idx] = (__bf16)v;
}

// ========== D1: round-5 structure (control), rows 0..50047, grid 782 ==========
__global__ void __launch_bounds__(512, 4)
gemm_signs_a(const float* __restrict__ basis,
             const __bf16* __restrict__ W,
             uint64_t* __restrict__ sbits) {
    __shared__ char smem[49152];   // A: [2][128r][64B] @0; B: [2][256c][64B] @16384

    const int tid    = threadIdx.x;
    const int lane   = tid & 63;
    const int wave   = tid >> 6;
    const int wr     = wave >> 2;
    const int wc     = wave & 3;
    const int lane16 = lane & 15;
    const int lgrp   = lane >> 4;

    // bijective XCD swizzle: nwg=782 = 8*97+6 (m204)
    const int orig = blockIdx.x;
    const int xcd  = orig & 7;
    const int wgid = (xcd < 6 ? xcd * 98 : 588 + (xcd - 6) * 97) + (orig >> 3);
    const int bn   = wgid & 1;
    const int bm   = wgid >> 1;    // 0..390

    const int ar = tid >> 2;
    const int ah = tid & 3;
    int arg = bm * 128 + ar;       // < 50048, no clamp needed
    const float* abase_g = basis + (size_t)arg * 512 + ah * 8;
    const int awofs = ar * 64 + ((ah ^ (ar & 3)) << 4);

    auto stage_B = [&](int t) {
        char* bbase = smem + 16384 + ((t & 1) << 14);
        #pragma unroll
        for (int i = 0; i < 2; ++i) {
            int c = wave * 32 + i * 16 + (lane >> 2);
            int g = lane & 3;
            const __bf16* src = W + (size_t)(bn * 256 + c) * 512 + t * 32
                                  + ((g ^ ((c >> 1) & 3)) << 3);
            gl_lds16(src, bbase + (wave * 32 + i * 16) * 64);
        }
    };

    f32x4  acc[4][4] = {};
    float4 ra[2][2];

    ra[0][0] = *(const float4*)(abase_g);
    ra[0][1] = *(const float4*)(abase_g + 4);
    ra[1][0] = *(const float4*)(abase_g + 32);
    ra[1][1] = *(const float4*)(abase_g + 36);
    stage_B(0);
    asm volatile("s_waitcnt vmcnt(4)" ::: "memory");
    {
        bf16x8 a8;
        a8[0] = (__bf16)ra[0][0].x; a8[1] = (__bf16)ra[0][0].y;
        a8[2] = (__bf16)ra[0][0].z; a8[3] = (__bf16)ra[0][0].w;
        a8[4] = (__bf16)ra[0][1].x; a8[5] = (__bf16)ra[0][1].y;
        a8[6] = (__bf16)ra[0][1].z; a8[7] = (__bf16)ra[0][1].w;
        *(bf16x8*)(smem + awofs) = a8;
    }

    #pragma unroll
    for (int t = 0; t < 16; ++t) {
        const int q = (t + 1) & 1;
        if (t < 14) {
            ra[t & 1][0] = *(const float4*)(abase_g + (t + 2) * 32);
            ra[t & 1][1] = *(const float4*)(abase_g + (t + 2) * 32 + 4);
        }
        if (t < 15) stage_B(t + 1);

        if      (t < 14) asm volatile("s_waitcnt vmcnt(4)\ns_barrier" ::: "memory");
        else if (t == 14) asm volatile("s_waitcnt vmcnt(2)\ns_barrier" ::: "memory");
        else              asm volatile("s_waitcnt vmcnt(0)\ns_barrier" ::: "memory");

        const char* ab = smem + ((t & 1) << 13);
        const char* bb = smem + 16384 + ((t & 1) << 14);

        bf16x8 bf[4];
        #pragma unroll
        for (int n = 0; n < 4; ++n) {
            int cc = wc * 64 + n * 16 + lane16;
            int gb = lgrp ^ ((cc >> 1) & 3);
            bf[n] = *(const bf16x8*)(bb + cc * 64 + gb * 16);
        }
        bf16x8 af[4];
        #pragma unroll
        for (int m = 0; m < 4; ++m) {
            int rr = wr * 64 + m * 16 + lane16;
            af[m] = *(const bf16x8*)(ab + rr * 64 + ((lgrp ^ (rr & 3)) << 4));
        }

        __builtin_amdgcn_s_setprio(1);
        #pragma unroll
        for (int m = 0; m < 4; ++m)
            #pragma unroll
            for (int n = 0; n < 4; ++n)
                acc[m][n] = __builtin_amdgcn_mfma_f32_16x16x32_bf16(
                    af[m], bf[n], acc[m][n], 0, 0, 0);
        __builtin_amdgcn_s_setprio(0);

        if (t < 15) {
            bf16x8 a8;
            a8[0] = (__bf16)ra[(t + 1) & 1][0].x; a8[1] = (__bf16)ra[(t + 1) & 1][0].y;
            a8[2] = (__bf16)ra[(t + 1) & 1][0].z; a8[3] = (__bf16)ra[(t + 1) & 1][0].w;
            a8[4] = (__bf16)ra[(t + 1) & 1][1].x; a8[5] = (__bf16)ra[(t + 1) & 1][1].y;
            a8[6] = (__bf16)ra[(t + 1) & 1][1].z; a8[7] = (__bf16)ra[(t + 1) & 1][1].w;
            *(bf16x8*)(smem + (q << 13) + awofs) = a8;
        }
        asm volatile("s_waitcnt lgkmcnt(0)\ns_barrier" ::: "memory");
    }

    unsigned char* sb = (unsigned char*)smem;     // [256 cols][136B]
    #pragma unroll
    for (int m = 0; m < 4; ++m) {
        #pragma unroll
        for (int n = 0; n < 4; ++n) {
            int cc = wc * 64 + n * 16 + lane16;
            int rb = wr * 64 + m * 16 + lgrp * 4;
            uint32_t pk = 0;
            #pragma unroll
            for (int r = 0; r < 4; ++r)
                pk |= (acc[m][n][r] < 0.0f ? 1u : 0u) << (8 * r);
            *(uint32_t*)&sb[cc * 136 + rb] = pk;
        }
    }
    asm volatile("s_waitcnt lgkmcnt(0)\ns_barrier" ::: "memory");
    {
        const int col = tid & 255;
        const int wh  = tid >> 8;
        const unsigned char* src = &sb[col * 136 + wh * 64];
        uint64_t wbits = 0;
        #pragma unroll
        for (int k = 0; k < 16; ++k) {
            uint32_t qv = *(const uint32_t*)&src[4 * k];
            uint32_t p4 = ((qv & 0x01010101u) * 0x10204080u) >> 28;
            wbits |= (uint64_t)p4 << (4 * k);
        }
        sbits[(size_t)(bm * 2 + wh) * 512 + bn * 256 + col] = wbits;
    }
}

// ========== D2: barrier-free wave-private, rows 50048.., grid 1568 ==========
// 4 waves/block; block-tile 256r x 64c; wave-tile 64x64. Per wave: A 4KB
// (reg-staged f32->bf16, swizzled ds_write) + B 4KB (DMA, source-swizzled),
// single-buffered, wave-private => NO s_barrier in K-loop. Ordering: own-wave
// lgkmcnt(0) before issuing next-tile loads (reads complete before overwrite),
// vmcnt counts for load arrival.
__global__ void __launch_bounds__(256, 3)
gemm_signs_b(const float* __restrict__ basis,
             const __bf16* __restrict__ W,
             uint64_t* __restrict__ sbits) {
    __shared__ char smem[32768];   // wave w: A @ w*8192 (4KB), B @ w*8192+4096

    const int tid    = threadIdx.x;
    const int lane   = tid & 63;
    const int wave   = tid >> 6;
    const int lane16 = lane & 15;
    const int lgrp   = lane >> 4;

    // XCD swizzle: 1568 = 8*196 exactly
    const int orig = blockIdx.x;
    const int lid  = (orig & 7) * 196 + (orig >> 3);
    const int bn   = lid & 7;      // 0..7 (64-col panel)
    const int bm   = lid >> 3;     // 0..195

    char* aw = smem + wave * 8192;
    char* bw = aw + 4096;
    const int rowbase = 50048 + bm * 256 + wave * 64;
    const int arl = lane >> 3;     // row-in-8
    const int agk = lane & 7;      // 16B f32 k-granule

    auto stage_B = [&](int t) {
        #pragma unroll
        for (int i = 0; i < 4; ++i) {
            int c = i * 16 + (lane >> 2);
            int g = lane & 3;
            const __bf16* src = W + (size_t)(bn * 64 + c) * 512 + t * 32
                                  + ((g ^ ((c >> 1) & 3)) << 3);
            gl_lds16(src, bw + i * 1024);
        }
    };
    float4 ra[8];
    auto load_A = [&](int t) {
        #pragma unroll
        for (int i = 0; i < 8; ++i) {
            int r = rowbase + arl + 8 * i;
            if (r > 99999) r = 99999;   // tail clamp (bits masked/skipped later)
            ra[i] = *(const float4*)(basis + (size_t)r * 512 + t * 32 + agk * 4);
        }
    };
    auto write_A = [&]() {
        #pragma unroll
        for (int i = 0; i < 8; ++i) {
            int rl = arl + 8 * i;
            bf16x4 v;
            v[0] = (__bf16)ra[i].x; v[1] = (__bf16)ra[i].y;
            v[2] = (__bf16)ra[i].z; v[3] = (__bf16)ra[i].w;
            *(bf16x4*)(aw + rl * 64 + (((agk >> 1) ^ (rl & 3)) << 4)
                       + ((agk & 1) << 3)) = v;
        }
    };

    f32x4 acc[4][4] = {};

    // prologue: A(0) (8 loads, oldest) then B(0) DMA (4); wait A only
    load_A(0);
    stage_B(0);
    asm volatile("s_waitcnt vmcnt(4)" ::: "memory");
    write_A();

    #pragma unroll
    for (int t = 0; t < 16; ++t) {
        // B(t) DMA landed + own A ds_writes done
        asm volatile("s_waitcnt vmcnt(0) lgkmcnt(0)" ::: "memory");
        __builtin_amdgcn_sched_barrier(0);

        bf16x8 af[4], bf[4];
        #pragma unroll
        for (int m = 0; m < 4; ++m) {
            int rr = m * 16 + lane16;
            af[m] = *(const bf16x8*)(aw + rr * 64 + ((lgrp ^ (rr & 3)) << 4));
        }
        #pragma unroll
        for (int n = 0; n < 4; ++n) {
            int cc = n * 16 + lane16;
            bf[n] = *(const bf16x8*)(bw + cc * 64 + ((lgrp ^ ((cc >> 1) & 3)) << 4));
        }
        asm volatile("s_waitcnt lgkmcnt(0)" ::: "memory");   // reads done: LDS reusable
        __builtin_amdgcn_sched_barrier(0);

        if (t < 15) { load_A(t + 1); stage_B(t + 1); }       // A first, then B
        __builtin_amdgcn_sched_barrier(0);

        __builtin_amdgcn_s_setprio(1);
        #pragma unroll
        for (int m = 0; m < 4; ++m)
            #pragma unroll
            for (int n = 0; n < 4; ++n)
                acc[m][n] = __builtin_amdgcn_mfma_f32_16x16x32_bf16(
                    af[m], bf[n], acc[m][n], 0, 0, 0);
        __builtin_amdgcn_s_setprio(0);

        if (t < 15) {
            asm volatile("s_waitcnt vmcnt(4)" ::: "memory");  // A(t+1) regs done, B flying
            __builtin_amdgcn_sched_barrier(0);
            write_A();
        }
    }

    // ---- epilogue: block-wide transpose/pack (barriers OK here) ----
    asm volatile("s_waitcnt lgkmcnt(0)" ::: "memory");
    __syncthreads();
    unsigned char* sb = (unsigned char*)smem;   // [64 cols][264B] = 16.9KB
    #pragma unroll
    for (int m = 0; m < 4; ++m) {
        #pragma unroll
        for (int n = 0; n < 4; ++n) {
            int cc = n * 16 + lane16;                 // local col 0..63
            int rb = wave * 64 + m * 16 + lgrp * 4;   // local row 0..255
            uint32_t pk = 0;
            #pragma unroll
            for (int r = 0; r < 4; ++r)
                pk |= (acc[m][n][r] < 0.0f ? 1u : 0u) << (8 * r);
            *(uint32_t*)&sb[cc * 264 + rb] = pk;
        }
    }
    __syncthreads();
    {
        const int col = tid & 63;
        const int wh  = tid >> 6;   // 0..3
        const unsigned char* src = &sb[col * 264 + wh * 64];
        uint64_t wbits = 0;
        #pragma unroll
        for (int k = 0; k < 16; ++k) {
            uint32_t qv = *(const uint32_t*)&src[4 * k];
            uint32_t p4 = ((qv & 0x01010101u) * 0x10204080u) >> 28;
            wbits |= (uint64_t)p4 << (4 * k);
        }
        int word = 782 + bm * 4 + wh;
        if (word < NWORDS)
            sbits[(size_t)word * 512 + bn * 64 + col] = wbits;
    }
}

// ---------- K2: crossing masks from sign bits ----------
__global__ void crossing_masks(const uint64_t* __restrict__ sbits,
                               uint64_t* __restrict__ maskT) {
    const int w = blockIdx.x;
    const int j = threadIdx.x;
    uint64_t s0r = sbits[(size_t)w * 512 + j];
    uint64_t s0p = sbits[(size_t)w * 512 + 256 + j];
    uint64_t s1r = sbits[(size_t)(w + 1) * 512 + j];
    uint64_t s1p = sbits[(size_t)(w + 1) * 512 + 256 + j];
    uint64_t cr = s0r ^ ((s0r >> 1) | (s1r << 63));
    uint64_t cp = s0p ^ ((s0p >> 1) | (s1p << 63));
    uint64_t m = cr & cp;
    if (w == NW - 1) m &= 0x7FFFFFFFull;
    maskT[(size_t)w * 256 + j] = m;
}

// ---------- K3: pairwise AND-popcount ----------
__global__ void zero_out(float* __restrict__ out) {
    int i = blockIdx.x * 256 + threadIdx.x;
    if (i < 32640) out[i] = 0.0f;
}

__global__ void pair_popcount(const uint64_t* __restrict__ maskT,
                              float* __restrict__ out) {
    const int i = blockIdx.x;
    const int c = blockIdx.y;
    const int j = threadIdx.x;
    if (j <= i) return;
    int w0 = c * 196;
    int w1 = w0 + 196; if (w1 > NW) w1 = NW;
    uint32_t sum = 0;
    #pragma unroll 4
    for (int w = w0; w < w1; ++w) {
        uint64_t mi = maskT[(size_t)w * 256 + i];
        uint64_t mj = maskT[(size_t)w * 256 + j];
        sum += (uint32_t)__popcll(mi & mj);
    }
    const size_t idx = (size_t)i * (2 * KDIM - i - 1) / 2 + (size_t)(j - i - 1);
    atomicAdd(&out[idx], (float)sum);
}

extern "C" void kernel_launch(void* const* d_in, const int* in_sizes, int n_in,
                              void* d_out, int out_size, void* d_ws, size_t ws_size,
                              hipStream_t stream) {
    const float* theta = (const float*)d_in[0];
    const float* basis = (const float*)d_in[1];
    const float* noise = (const float*)d_in[2];
    float* out = (float*)d_out;

    char* ws = (char*)d_ws;
    __bf16*   W     = (__bf16*)ws;
    uint64_t* sbits = (uint64_t*)(ws + 524288);
    uint64_t* maskT = (uint64_t*)(ws + 524288 + (size_t)NWORDS * 512 * 8);

    hipLaunchKernelGGL(build_w,        dim3(1024),    dim3(256), 0, stream, theta, noise, W);
    hipLaunchKernelGGL(gemm_signs_a,   dim3(782),     dim3(512), 0, stream, basis, W, sbits);
    hipLaunchKernelGGL(gemm_signs_b,   dim3(1568),    dim3(256), 0, stream, basis, W, sbits);
    hipLaunchKernelGGL(crossing_masks, dim3(NW),      dim3(256), 0, stream, sbits, maskT);
    hipLaunchKernelGGL(zero_out,       dim3(128),     dim3(256), 0, stream, out);
    hipLaunchKernelGGL(pair_popcount,  dim3(KDIM, 8), dim3(256), 0, stream, maskT, out);
}

// Round 8
// 122.281 us; speedup vs baseline: 1.3616x; 1.2714x over previous
//
#include <hip/hip_runtime.h>
#include <hip/hip_bf16.h>
#include <stdint.h>

#define KDIM    256
#define NWORDS  1564         // sign words per column
#define NW      1563         // crossing words (ceil(99999/64))
#define GEMM_GRID 1564       // 782 bm * 2 bn

typedef float  f32x4  __attribute__((ext_vector_type(4)));
typedef __bf16 bf16x8 __attribute__((ext_vector_type(8)));

__device__ __forceinline__ void gl_lds16(const void* g, void* l) {
    __builtin_amdgcn_global_load_lds(
        (const __attribute__((address_space(1))) unsigned int*)g,
        (__attribute__((address_space(3))) unsigned int*)l, 16, 0, 0);
}

// ---------- K0: build W, tile-major + read-swizzle pre-applied ----------
// Wt layout: [kt 0..15][j 0..511][32 bf16], with the 16B granule g of each
// row-tile stored at slot g ^ ((j>>1)&3) (the ds_read-side involution).
// A K-step's B panel (kt, j in [bn*256, bn*256+256)) is then 16KB CONTIGUOUS
// and global_load_lds copies it linearly (coalesced, no line amplification).
__global__ void build_w(const float* __restrict__ theta,
                        const float* __restrict__ noise,
                        __bf16* __restrict__ Wt) {
    int idx = blockIdx.x * 256 + threadIdx.x;   // 0..262143
    int j = idx >> 9;
    int d = idx & 511;
    float v;
    if (j < KDIM) v = theta[j * 512 + d];
    else          v = theta[(j - KDIM) * 512 + d] + 0.01f * noise[(j - KDIM) * 512 + d];
    int t  = d >> 5;
    int g  = (d >> 3) & 3;
    int e  = d & 7;
    int gs = g ^ ((j >> 1) & 3);
    Wt[(((t << 9) + j) << 5) + (gs << 3) + e] = (__bf16)v;
}

// ---------- K1: MFMA GEMM -> packed sign bits ----------
// BM=128 x BN=256, BK=32, 512 threads (8 waves 2Mx4N, wave-tile 64x64).
// ONE barrier per K-step. A: global f32 -> regs (distance 2) -> cvt ->
// XOR-swizzled ds_write (post-MFMA). B: linear global_load_lds from the
// pre-swizzled tile-major Wt, issued POST-barrier (distance 1, race-free).
// Steady-state wait: vmcnt(2) = {B(t) DMA, A(t+1) regs}; loads never fully
// drain until the tail. LDS 48KB (A 2x8KB + B 2x16KB), 3 blocks/CU by LDS.
__global__ void __launch_bounds__(512, 4)
gemm_signs(const float* __restrict__ basis,
           const __bf16* __restrict__ Wt,
           uint64_t* __restrict__ sbits) {
    __shared__ char smem[49152];   // A: [2][128r][64B] @0; B: [2][16KB] @16384

    const int tid    = threadIdx.x;
    const int lane   = tid & 63;
    const int wave   = tid >> 6;
    const int wr     = wave >> 2;
    const int wc     = wave & 3;
    const int lane16 = lane & 15;
    const int lgrp   = lane >> 4;

    // bijective XCD swizzle: nwg=1564=8*195+4 (m204)
    const int orig = blockIdx.x;
    const int xcd  = orig & 7;
    const int wgid = (xcd < 4 ? xcd * 196 : 784 + (xcd - 4) * 195) + (orig >> 3);
    const int bn   = wgid & 1;
    const int bm   = wgid >> 1;    // 0..781

    // ---- A staging: thread -> (row ar, 16B-granule ah of 64B bf16 row) ----
    const int ar = tid >> 2;
    const int ah = tid & 3;
    int arg = bm * 128 + ar; if (arg > 99999) arg = 99999;   // tail clamp
    const float* abase_g = basis + (size_t)arg * 512 + ah * 8;
    const int awofs = ar * 64 + ((ah ^ (ar & 3)) << 4);

    // ---- B staging: pure linear DMA, 2KB per wave per K-step ----
    const char* bpanel = (const char*)Wt + ((size_t)bn * 256 << 6) + wave * 2048 + lane * 16;
    auto stage_B = [&](int t) {
        char* bdst = smem + 16384 + ((t & 1) << 14) + wave * 2048;
        const char* src = bpanel + ((size_t)t << 15);   // t*512 rows * 64B
        gl_lds16(src,        bdst);
        gl_lds16(src + 1024, bdst + 1024);
    };

    f32x4  acc[4][4] = {};
    float4 ra[2][2];

    auto cvt_write_A = [&](int slot, int q) {
        bf16x8 a8;
        a8[0] = (__bf16)ra[slot][0].x; a8[1] = (__bf16)ra[slot][0].y;
        a8[2] = (__bf16)ra[slot][0].z; a8[3] = (__bf16)ra[slot][0].w;
        a8[4] = (__bf16)ra[slot][1].x; a8[5] = (__bf16)ra[slot][1].y;
        a8[6] = (__bf16)ra[slot][1].z; a8[7] = (__bf16)ra[slot][1].w;
        *(bf16x8*)(smem + (q << 13) + awofs) = a8;
    };

    // ---- prologue: A(0),A(1) loads; B(0) DMA; write As[0] ----
    ra[0][0] = *(const float4*)(abase_g);
    ra[0][1] = *(const float4*)(abase_g + 4);
    ra[1][0] = *(const float4*)(abase_g + 32);
    ra[1][1] = *(const float4*)(abase_g + 36);
    stage_B(0);
    asm volatile("s_waitcnt vmcnt(4)" ::: "memory");   // A(0) regs ready
    cvt_write_A(0, 0);
    asm volatile("s_waitcnt lgkmcnt(0)" ::: "memory");

    #pragma unroll
    for (int t = 0; t < 16; ++t) {
        // 1) issue A(t+2) (distance 2; stays in flight across the barrier)
        if (t < 14) {
            ra[t & 1][0] = *(const float4*)(abase_g + (t + 2) * 32);
            ra[t & 1][1] = *(const float4*)(abase_g + (t + 2) * 32 + 4);
        }

        // 2) counted drain {A(t+1), B(t)} + the tile barrier (ONE per K-step)
        if (t < 14) asm volatile("s_waitcnt vmcnt(2)\ns_barrier" ::: "memory");
        else        asm volatile("s_waitcnt vmcnt(0)\ns_barrier" ::: "memory");

        // 3) B(t+1) DMA into parity q -- post-barrier, so all reads of q
        //    (done at t-1, lgkm0'd before this barrier) have completed.
        if (t < 15) stage_B(t + 1);

        const char* ab = smem + ((t & 1) << 13);
        const char* bb = smem + 16384 + ((t & 1) << 14);

        // 4) fragments + MFMA
        bf16x8 bf[4];
        #pragma unroll
        for (int n = 0; n < 4; ++n) {
            int cc = wc * 64 + n * 16 + lane16;
            bf[n] = *(const bf16x8*)(bb + cc * 64 + ((lgrp ^ ((cc >> 1) & 3)) << 4));
        }
        bf16x8 af[4];
        #pragma unroll
        for (int m = 0; m < 4; ++m) {
            int rr = wr * 64 + m * 16 + lane16;
            af[m] = *(const bf16x8*)(ab + rr * 64 + ((lgrp ^ (rr & 3)) << 4));
        }
        asm volatile("s_waitcnt lgkmcnt(0)" ::: "memory");
        __builtin_amdgcn_sched_barrier(0);

        __builtin_amdgcn_s_setprio(1);
        #pragma unroll
        for (int m = 0; m < 4; ++m)
            #pragma unroll
            for (int n = 0; n < 4; ++n)
                acc[m][n] = __builtin_amdgcn_mfma_f32_16x16x32_bf16(
                    af[m], bf[n], acc[m][n], 0, 0, 0);
        __builtin_amdgcn_s_setprio(0);

        // 5) cvt + ds_write A(t+1) into parity q; visible at next barrier
        if (t < 15) {
            cvt_write_A((t + 1) & 1, (t + 1) & 1);
            asm volatile("s_waitcnt lgkmcnt(0)" ::: "memory");
        }
    }

    // ---- epilogue: sign bytes -> LDS transpose -> multiply-pack -> u64 ----
    asm volatile("s_barrier" ::: "memory");       // all waves done with K-loop LDS
    unsigned char* sb = (unsigned char*)smem;     // [256 cols][136B] = 34.8KB
    #pragma unroll
    for (int m = 0; m < 4; ++m) {
        #pragma unroll
        for (int n = 0; n < 4; ++n) {
            int cc = wc * 64 + n * 16 + lane16;          // local col 0..255
            int rb = wr * 64 + m * 16 + lgrp * 4;        // local row base
            uint32_t pk = 0;
            #pragma unroll
            for (int r = 0; r < 4; ++r)
                pk |= (acc[m][n][r] < 0.0f ? 1u : 0u) << (8 * r);
            *(uint32_t*)&sb[cc * 136 + rb] = pk;
        }
    }
    asm volatile("s_waitcnt lgkmcnt(0)\ns_barrier" ::: "memory");

    {   // thread -> (col 0..255, word-half 0..1); 64 sign bytes -> u64
        const int col = tid & 255;
        const int wh  = tid >> 8;
        const unsigned char* src = &sb[col * 136 + wh * 64];
        uint64_t wbits = 0;
        #pragma unroll
        for (int k = 0; k < 16; ++k) {
            uint32_t qv = *(const uint32_t*)&src[4 * k];
            uint32_t p4 = ((qv & 0x01010101u) * 0x10204080u) >> 28;
            wbits |= (uint64_t)p4 << (4 * k);
        }
        sbits[(size_t)(bm * 2 + wh) * 512 + bn * 256 + col] = wbits;  // coalesced
    }
}

// ---------- K2: crossing masks from sign bits ----------
__global__ void crossing_masks(const uint64_t* __restrict__ sbits,
                               uint64_t* __restrict__ maskT) {
    const int w = blockIdx.x;
    const int j = threadIdx.x;
    uint64_t s0r = sbits[(size_t)w * 512 + j];
    uint64_t s0p = sbits[(size_t)w * 512 + 256 + j];
    uint64_t s1r = sbits[(size_t)(w + 1) * 512 + j];
    uint64_t s1p = sbits[(size_t)(w + 1) * 512 + 256 + j];
    uint64_t cr = s0r ^ ((s0r >> 1) | (s1r << 63));
    uint64_t cp = s0p ^ ((s0p >> 1) | (s1p << 63));
    uint64_t m = cr & cp;
    if (w == NW - 1) m &= 0x7FFFFFFFull;    // 31 valid crossings in last word
    maskT[(size_t)w * 256 + j] = m;
}

// ---------- K3: pairwise AND-popcount ----------
__global__ void zero_out(float* __restrict__ out) {
    int i = blockIdx.x * 256 + threadIdx.x;
    if (i < 32640) out[i] = 0.0f;
}

__global__ void pair_popcount(const uint64_t* __restrict__ maskT,
                              float* __restrict__ out) {
    const int i = blockIdx.x;
    const int c = blockIdx.y;
    const int j = threadIdx.x;
    if (j <= i) return;
    int w0 = c * 196;
    int w1 = w0 + 196; if (w1 > NW) w1 = NW;
    uint32_t sum = 0;
    #pragma unroll 4
    for (int w = w0; w < w1; ++w) {
        uint64_t mi = maskT[(size_t)w * 256 + i];   // block-uniform -> scalar
        uint64_t mj = maskT[(size_t)w * 256 + j];   // coalesced
        sum += (uint32_t)__popcll(mi & mj);
    }
    const size_t idx = (size_t)i * (2 * KDIM - i - 1) / 2 + (size_t)(j - i - 1);
    atomicAdd(&out[idx], (float)sum);   // exact-integer f32 adds -> deterministic
}

extern "C" void kernel_launch(void* const* d_in, const int* in_sizes, int n_in,
                              void* d_out, int out_size, void* d_ws, size_t ws_size,
                              hipStream_t stream) {
    const float* theta = (const float*)d_in[0];
    const float* basis = (const float*)d_in[1];
    const float* noise = (const float*)d_in[2];
    float* out = (float*)d_out;

    char* ws = (char*)d_ws;
    __bf16*   Wt    = (__bf16*)ws;                              // 512 KB, tile-major
    uint64_t* sbits = (uint64_t*)(ws + 524288);                 // 6.41 MB
    uint64_t* maskT = (uint64_t*)(ws + 524288 + (size_t)NWORDS * 512 * 8); // 3.2 MB

    hipLaunchKernelGGL(build_w,        dim3(1024),     dim3(256), 0, stream, theta, noise, Wt);
    hipLaunchKernelGGL(gemm_signs,     dim3(GEMM_GRID),dim3(512), 0, stream, basis, Wt, sbits);
    hipLaunchKernelGGL(crossing_masks, dim3(NW),       dim3(256), 0, stream, sbits, maskT);
    hipLaunchKernelGGL(zero_out,       dim3(128),      dim3(256), 0, stream, out);
    hipLaunchKernelGGL(pair_popcount,  dim3(KDIM, 8),  dim3(256), 0, stream, maskT, out);
}